// Round 4
// baseline (9809.961 us; speedup 1.0000x reference)
//
#include <hip/hip_runtime.h>
#include <hip/hip_bf16.h>

// R4: single-block-per-group recurrence — the whole 512-col Whh lives in one CU's
// unified VGPR/AGPR file (64 bf16x8 frags/wave x 8 waves = 512 KB). h exchange is
// intra-block via double-buffered LDS + ONE barrier/step. No cross-block sync.
// All dtype normalization done inline (detect_dtype probe + branches); 6 launches.

typedef __attribute__((ext_vector_type(8))) short bf16x8;
typedef __attribute__((ext_vector_type(4))) float f32x4;

#define T_STEPS 512
#define NBATCH  128
#define HID     512
#define INSZ    256
#define LROW    520   // LDS row stride (shorts)

static __device__ __forceinline__ float bf2f(__hip_bfloat16 v) { return __bfloat162float(v); }
static __device__ __forceinline__ __hip_bfloat16 f2bf(float v) { return __float2bfloat16(v); }

union BF8 { bf16x8 v; unsigned short u[8]; };
static __device__ __forceinline__ unsigned short f2bfbits(float x) {
    __hip_bfloat16 b = __float2bfloat16(x);
    return *reinterpret_cast<unsigned short*>(&b);
}
static __device__ __forceinline__ float loadE(const void* p, size_t i, bool f32) {
    return f32 ? ((const float*)p)[i] : bf2f(((const __hip_bfloat16*)p)[i]);
}
// tanh(x) = 1 - 2/(e^{2x}+1); exp over/underflow saturates correctly to +-1.
static __device__ __forceinline__ float fast_tanh(float x) {
    float e = __expf(2.f * x);
    float r = __builtin_amdgcn_rcpf(e + 1.f);
    return 1.f - 2.f * r;
}

// ---------------- dtype probe: even uint16s of fp32 data are random mantissa halves
__global__ void detect_dtype(const unsigned short* __restrict__ x, unsigned int* __restrict__ dflag) {
    if (threadIdx.x == 0 && blockIdx.x == 0) {
        int sane = 0;
        for (int i = 0; i < 64; ++i) {
            unsigned short v = x[2 * i];
            unsigned int e = (v >> 7) & 0xFF;
            if (v == 0 || (e >= 0x60 && e <= 0x9F)) ++sane;
        }
        *dflag = (sane >= 48) ? 0u : 1u;  // 0 = bf16 data, 1 = fp32 data
    }
}

// ---------------- GEMM: out[M][N] = A[M][K] @ W[N][K]^T + b1[N] (+ b2[N])
__global__ __launch_bounds__(256, 4) void gemm_bt64(
    const void* __restrict__ A, const void* __restrict__ W,
    const void* __restrict__ b1, const void* __restrict__ b2,
    void* __restrict__ out, int M, int N, int K,
    const int* __restrict__ lengths, const unsigned int* __restrict__ dflag,
    int aIsOrig, int outIsOutput)
{
    const int r0 = blockIdx.y * 64;
    if (lengths) {  // rows are (t*128+n); a 64-row tile is one t, n0 in {0,64}; sorted desc.
        int t = r0 >> 7, n0 = r0 & 127;
        if (lengths[n0] <= t) return;
    }
    const bool f32 = *dflag != 0;
    const int c0 = blockIdx.x * 64;
    __shared__ short As[64 * 32];
    __shared__ short Bs[64 * 32];
    const int tid = threadIdx.x;
    const int lane = tid & 63, wave = tid >> 6;
    const int lrow = tid >> 2, lk = (tid & 3) * 8;
    const int q = (lane >> 4) & 3, l15 = lane & 15;

    f32x4 z = {0.f, 0.f, 0.f, 0.f};
    f32x4 acc[4];
#pragma unroll
    for (int m = 0; m < 4; ++m) acc[m] = z;

    for (int kk = 0; kk < K; kk += 32) {
        if (aIsOrig && f32) {
            const float* f = (const float*)A + (size_t)(r0 + lrow) * K + kk + lk;
            BF8 u;
#pragma unroll
            for (int i = 0; i < 8; ++i) u.u[i] = f2bfbits(f[i]);
            *(bf16x8*)&As[lrow * 32 + lk] = u.v;
        } else {
            *(bf16x8*)&As[lrow * 32 + lk] =
                *(const bf16x8*)((const __hip_bfloat16*)A + (size_t)(r0 + lrow) * K + kk + lk);
        }
        if (f32) {
            const float* f = (const float*)W + (size_t)(c0 + lrow) * K + kk + lk;
            BF8 u;
#pragma unroll
            for (int i = 0; i < 8; ++i) u.u[i] = f2bfbits(f[i]);
            *(bf16x8*)&Bs[lrow * 32 + lk] = u.v;
        } else {
            *(bf16x8*)&Bs[lrow * 32 + lk] =
                *(const bf16x8*)((const __hip_bfloat16*)W + (size_t)(c0 + lrow) * K + kk + lk);
        }
        __syncthreads();
        bf16x8 bfrag = *(const bf16x8*)&Bs[(wave * 16 + l15) * 32 + q * 8];
#pragma unroll
        for (int m = 0; m < 4; ++m) {
            bf16x8 afrag = *(const bf16x8*)&As[(m * 16 + l15) * 32 + q * 8];
            acc[m] = __builtin_amdgcn_mfma_f32_16x16x32_bf16(afrag, bfrag, acc[m], 0, 0, 0);
        }
        __syncthreads();
    }
    const int col = c0 + wave * 16 + l15;
    float bias = loadE(b1, col, f32) + (b2 ? loadE(b2, col, f32) : 0.f);
#pragma unroll
    for (int m = 0; m < 4; ++m) {
#pragma unroll
        for (int r = 0; r < 4; ++r) {
            int row = r0 + m * 16 + q * 4 + r;
            float v = acc[m][r] + bias;
            if (outIsOutput && f32) ((float*)out)[(size_t)row * N + col] = v;
            else ((__hip_bfloat16*)out)[(size_t)row * N + col] = f2bf(v);
        }
    }
}

// ---------------- recurrence: grid = 8 blocks (one per 16-sample group), 512 thr.
// Wave w owns output cols [w*64, w*64+64); full Whh resident as 64 B-frags/wave.
__global__ __launch_bounds__(512, 2) void rnn_recur(
    const __hip_bfloat16* __restrict__ xp,    // [T*128][512] bf16 (ws)
    const void* __restrict__ Whh,             // [512][512] orig dtype
    const void* __restrict__ h0all,           // [2][128][512] orig dtype (layer-sliced here)
    int layer,
    const int* __restrict__ lengths,          // [128] sorted desc
    __hip_bfloat16* __restrict__ out0,        // [T*128][512] bf16 or nullptr
    void* __restrict__ hout,                  // d_out base; final h at elem houtOff
    int houtOff,
    __hip_bfloat16* __restrict__ hfbf,        // [128][512] final h bf16 (logits input)
    const unsigned int* __restrict__ dflag)
{
    const int gb = blockIdx.x;
    const int s0 = gb * 16;
    const int tid = threadIdx.x, lane = tid & 63, wave = tid >> 6;
    const int q = (lane >> 4) & 3, l15 = lane & 15;
    const int colW = wave * 64;
    const bool f32 = *dflag != 0;
    const size_t h0base = (size_t)layer * NBATCH * HID;  // element offset into h0all
    __shared__ short hlds[2 * 16 * LROW];

    // persistent B fragments: the wave's 64 cols, full K=512 (256 unified regs)
    bf16x8 bfr[4][16];
    if (f32) {
#pragma unroll
        for (int j = 0; j < 4; ++j)
#pragma unroll
            for (int c = 0; c < 16; ++c) {
                const float* f = (const float*)Whh + (size_t)(colW + j * 16 + l15) * HID + c * 32 + q * 8;
                BF8 u;
#pragma unroll
                for (int i = 0; i < 8; ++i) u.u[i] = f2bfbits(f[i]);
                bfr[j][c] = u.v;
            }
    } else {
#pragma unroll
        for (int j = 0; j < 4; ++j)
#pragma unroll
            for (int c = 0; c < 16; ++c)
                bfr[j][c] = *(const bf16x8*)((const __hip_bfloat16*)Whh +
                    (size_t)(colW + j * 16 + l15) * HID + c * 32 + q * 8);
    }

    int len_r[4];
#pragma unroll
    for (int r = 0; r < 4; ++r) len_r[r] = lengths[s0 + q * 4 + r];

    float cur[4][4];  // owned h: sample q*4+r, col colW + j*16 + l15
#pragma unroll
    for (int j = 0; j < 4; ++j)
#pragma unroll
        for (int r = 0; r < 4; ++r)
            cur[j][r] = loadE(h0all, h0base + (size_t)(s0 + q * 4 + r) * HID + colW + j * 16 + l15, f32);

    // stage S_0 (16 samples x 512 cols) into LDS buf 0
    {
        const int sr = tid >> 5, cb = (tid & 31) * 16;
        BF8 u0, u1;
#pragma unroll
        for (int i = 0; i < 8; ++i) {
            u0.u[i] = f2bfbits(loadE(h0all, h0base + (size_t)(s0 + sr) * HID + cb + i, f32));
            u1.u[i] = f2bfbits(loadE(h0all, h0base + (size_t)(s0 + sr) * HID + cb + 8 + i, f32));
        }
        *(bf16x8*)&hlds[sr * LROW + cb] = u0.v;
        *(bf16x8*)&hlds[sr * LROW + cb + 8] = u1.v;
    }
    __syncthreads();

    const int Tg = lengths[s0];   // group max length (sorted desc)

    // preload xp for t=0
    float xv[4][4];
    {
        const __hip_bfloat16* xprow = xp + (size_t)s0 * HID;
#pragma unroll
        for (int j = 0; j < 4; ++j)
#pragma unroll
            for (int r = 0; r < 4; ++r)
                xv[j][r] = bf2f(xprow[(size_t)(q * 4 + r) * HID + colW + j * 16 + l15]);
    }

    for (int t = 0; t < Tg; ++t) {
        const int cb_ = t & 1, nb = (t + 1) & 1;

        // A-frags for all 16 k-chunks (reused across the 4 col-frags)
        bf16x8 a[16];
#pragma unroll
        for (int c = 0; c < 16; ++c)
            a[c] = *(const bf16x8*)&hlds[cb_ * 16 * LROW + l15 * LROW + c * 32 + q * 8];

        // prefetch next step's xp (overlaps MFMA)
        float xn[4][4];
        if (t + 1 < Tg) {
            const __hip_bfloat16* xprow = xp + ((size_t)(t + 1) * NBATCH + s0) * HID;
#pragma unroll
            for (int j = 0; j < 4; ++j)
#pragma unroll
                for (int r = 0; r < 4; ++r)
                    xn[j][r] = bf2f(xprow[(size_t)(q * 4 + r) * HID + colW + j * 16 + l15]);
        }

        f32x4 zz = {0.f, 0.f, 0.f, 0.f};
        f32x4 acc[4] = {zz, zz, zz, zz};
#pragma unroll
        for (int j = 0; j < 4; ++j)
#pragma unroll
            for (int c = 0; c < 16; ++c)
                acc[j] = __builtin_amdgcn_mfma_f32_16x16x32_bf16(a[c], bfr[j][c], acc[j], 0, 0, 0);

#pragma unroll
        for (int j = 0; j < 4; ++j) {
#pragma unroll
            for (int r = 0; r < 4; ++r) {
                const int sl = q * 4 + r;
                float hnew = fast_tanh(acc[j][r] + xv[j][r]);
                float val = (t < len_r[r]) ? hnew : cur[j][r];
                cur[j][r] = val;
                unsigned short bits = f2bfbits(val);
                hlds[nb * 16 * LROW + sl * LROW + colW + j * 16 + l15] = (short)bits;
                if (out0 && t < len_r[r])
                    out0[((size_t)t * NBATCH + s0 + sl) * HID + colW + j * 16 + l15] =
                        *reinterpret_cast<__hip_bfloat16*>(&bits);
            }
        }
        __syncthreads();
#pragma unroll
        for (int j = 0; j < 4; ++j)
#pragma unroll
            for (int r = 0; r < 4; ++r) xv[j][r] = xn[j][r];
    }

    // finals: h to d_out (output dtype) and bf16 copy for logits GEMM
#pragma unroll
    for (int j = 0; j < 4; ++j)
#pragma unroll
        for (int r = 0; r < 4; ++r) {
            size_t idx = (size_t)(s0 + q * 4 + r) * HID + colW + j * 16 + l15;
            if (f32) ((float*)hout)[houtOff + idx] = cur[j][r];
            else     ((__hip_bfloat16*)hout)[houtOff + idx] = f2bf(cur[j][r]);
            hfbf[idx] = f2bf(cur[j][r]);
        }
}

extern "C" void kernel_launch(void* const* d_in, const int* in_sizes, int n_in,
                              void* d_out, int out_size, void* d_ws, size_t ws_size,
                              hipStream_t stream) {
    const void* x    = d_in[0];
    const void* h0   = d_in[1];
    const int*  lens = (const int*)d_in[2];
    const void* Wih0 = d_in[3];
    const void* bih0 = d_in[4];
    const void* Whh0 = d_in[5];
    const void* bhh0 = d_in[6];
    const void* Wih1 = d_in[7];
    const void* bih1 = d_in[8];
    const void* Whh1 = d_in[9];
    const void* bhh1 = d_in[10];
    const void* Wfc  = d_in[11];
    const void* bfc  = d_in[12];

    const size_t MROWS = (size_t)T_STEPS * NBATCH;          // 65536
    size_t off = 0;
    auto take = [&](size_t bytes) { size_t o = off; off += (bytes + 255) & ~255ull; return o; };
    const size_t off_xp   = take(MROWS * HID * 2);          // 64 MB bf16
    const size_t off_out0 = take(MROWS * HID * 2);          // 64 MB bf16
    const size_t off_hfbf = take(2ull * NBATCH * HID * 2);
    const size_t off_dfl  = take(256);
    if (ws_size < off) return;  // workspace too small

    char* ws = (char*)d_ws;
    __hip_bfloat16* xp    = (__hip_bfloat16*)(ws + off_xp);
    __hip_bfloat16* out0  = (__hip_bfloat16*)(ws + off_out0);
    __hip_bfloat16* hfbf  = (__hip_bfloat16*)(ws + off_hfbf);
    unsigned int*   dflag = (unsigned int*)(ws + off_dfl);

    detect_dtype<<<1, 64, 0, stream>>>((const unsigned short*)x, dflag);

    // layer 0 input GEMM: xp0 = x @ Wih0^T + bih0 + bhh0
    gemm_bt64<<<dim3(HID / 64, MROWS / 64), 256, 0, stream>>>(
        x, Wih0, bih0, bhh0, xp, (int)MROWS, HID, INSZ, lens, dflag, 1, 0);
    // layer 0 recurrence (writes out0 + final h into d_out at elem 16384)
    rnn_recur<<<8, 512, 0, stream>>>(
        xp, Whh0, h0, 0, lens, out0, d_out, NBATCH * 128, hfbf, dflag);
    // layer 1 input GEMM: xp1 = out0 @ Wih1^T + bih1 + bhh1 (reuse xp region)
    gemm_bt64<<<dim3(HID / 64, MROWS / 64), 256, 0, stream>>>(
        out0, Wih1, bih1, bhh1, xp, (int)MROWS, HID, HID, lens, dflag, 0, 0);
    // layer 1 recurrence (final h into d_out at elem 16384 + 65536)
    rnn_recur<<<8, 512, 0, stream>>>(
        xp, Whh1, h0, 1, lens, nullptr, d_out,
        NBATCH * 128 + NBATCH * HID, hfbf + (size_t)NBATCH * HID, dflag);
    // logits = h1_final @ Wfc^T + bfc
    gemm_bt64<<<dim3(2, 2), 256, 0, stream>>>(
        hfbf + (size_t)NBATCH * HID, Wfc, bfc, nullptr,
        d_out, NBATCH, 128, HID, nullptr, dflag, 0, 1);
}

// Round 5
// 2488.568 us; speedup vs baseline: 3.9420x; 3.9420x over previous
//
#include <hip/hip_runtime.h>
#include <hip/hip_bf16.h>

// R5: back to 2-block-per-group split (register-feasible, proven in R3) with the
// per-step sync path optimized:
//  - frag-major LDS layout for h (conflict-free ds_read_b128 A-frags)
//  - poll partner via 2x global_load_dwordx4 sc0 sc1 (inline asm), per-word tags
//  - s_sleep backoff in the spin to avoid L3 port thrash
//  - publish stores issued immediately after tanh
// Whh half (256 cols x 512 K bf16 = 128 regs/wave) persistent in unified RF.

typedef __attribute__((ext_vector_type(8))) short bf16x8;
typedef __attribute__((ext_vector_type(4))) float f32x4;

#define T_STEPS 512
#define NBATCH  128
#define HID     512
#define INSZ    256
#define HB      8192   // shorts per LDS h buffer (16 samples x 512 cols, frag-major)

static __device__ __forceinline__ float bf2f(__hip_bfloat16 v) { return __bfloat162float(v); }
static __device__ __forceinline__ __hip_bfloat16 f2bf(float v) { return __float2bfloat16(v); }

union BF8 { bf16x8 v; unsigned short u[8]; };
static __device__ __forceinline__ unsigned short f2bfbits(float x) {
    __hip_bfloat16 b = __float2bfloat16(x);
    return *reinterpret_cast<unsigned short*>(&b);
}
static __device__ __forceinline__ float loadE(const void* p, size_t i, bool f32) {
    return f32 ? ((const float*)p)[i] : bf2f(((const __hip_bfloat16*)p)[i]);
}
// tanh(x) = 1 - 2/(e^{2x}+1); exp over/underflow saturates correctly to +-1.
static __device__ __forceinline__ float fast_tanh(float x) {
    float e = __expf(2.f * x);
    float r = __builtin_amdgcn_rcpf(e + 1.f);
    return 1.f - 2.f * r;
}
// coherent (L2-bypass) 2x16B load — reaches the agent coherence point
static __device__ __forceinline__ void load2_coherent(const unsigned int* p, uint4& a, uint4& b) {
    asm volatile("global_load_dwordx4 %0, %2, off sc0 sc1\n\t"
                 "global_load_dwordx4 %1, %3, off sc0 sc1\n\t"
                 "s_waitcnt vmcnt(0)"
                 : "=v"(a), "=v"(b)
                 : "v"(p), "v"(p + 4)
                 : "memory");
}

// ---------------- dtype probe: even uint16s of fp32 data are random mantissa halves
__global__ void detect_dtype(const unsigned short* __restrict__ x, unsigned int* __restrict__ dflag) {
    if (threadIdx.x == 0 && blockIdx.x == 0) {
        int sane = 0;
        for (int i = 0; i < 64; ++i) {
            unsigned short v = x[2 * i];
            unsigned int e = (v >> 7) & 0xFF;
            if (v == 0 || (e >= 0x60 && e <= 0x9F)) ++sane;
        }
        *dflag = (sane >= 48) ? 0u : 1u;  // 0 = bf16 data, 1 = fp32 data
    }
}

// ---------------- GEMM: out[M][N] = A[M][K] @ W[N][K]^T + b1[N] (+ b2[N])
__global__ __launch_bounds__(256, 4) void gemm_bt64(
    const void* __restrict__ A, const void* __restrict__ W,
    const void* __restrict__ b1, const void* __restrict__ b2,
    void* __restrict__ out, int M, int N, int K,
    const int* __restrict__ lengths, const unsigned int* __restrict__ dflag,
    int aIsOrig, int outIsOutput)
{
    const int r0 = blockIdx.y * 64;
    if (lengths) {  // rows are (t*128+n); a 64-row tile is one t, n0 in {0,64}; sorted desc.
        int t = r0 >> 7, n0 = r0 & 127;
        if (lengths[n0] <= t) return;
    }
    const bool f32 = *dflag != 0;
    const int c0 = blockIdx.x * 64;
    __shared__ short As[64 * 32];
    __shared__ short Bs[64 * 32];
    const int tid = threadIdx.x;
    const int lane = tid & 63, wave = tid >> 6;
    const int lrow = tid >> 2, lk = (tid & 3) * 8;
    const int q = (lane >> 4) & 3, l15 = lane & 15;

    f32x4 z = {0.f, 0.f, 0.f, 0.f};
    f32x4 acc[4];
#pragma unroll
    for (int m = 0; m < 4; ++m) acc[m] = z;

    for (int kk = 0; kk < K; kk += 32) {
        if (aIsOrig && f32) {
            const float* f = (const float*)A + (size_t)(r0 + lrow) * K + kk + lk;
            BF8 u;
#pragma unroll
            for (int i = 0; i < 8; ++i) u.u[i] = f2bfbits(f[i]);
            *(bf16x8*)&As[lrow * 32 + lk] = u.v;
        } else {
            *(bf16x8*)&As[lrow * 32 + lk] =
                *(const bf16x8*)((const __hip_bfloat16*)A + (size_t)(r0 + lrow) * K + kk + lk);
        }
        if (f32) {
            const float* f = (const float*)W + (size_t)(c0 + lrow) * K + kk + lk;
            BF8 u;
#pragma unroll
            for (int i = 0; i < 8; ++i) u.u[i] = f2bfbits(f[i]);
            *(bf16x8*)&Bs[lrow * 32 + lk] = u.v;
        } else {
            *(bf16x8*)&Bs[lrow * 32 + lk] =
                *(const bf16x8*)((const __hip_bfloat16*)W + (size_t)(c0 + lrow) * K + kk + lk);
        }
        __syncthreads();
        bf16x8 bfrag = *(const bf16x8*)&Bs[(wave * 16 + l15) * 32 + q * 8];
#pragma unroll
        for (int m = 0; m < 4; ++m) {
            bf16x8 afrag = *(const bf16x8*)&As[(m * 16 + l15) * 32 + q * 8];
            acc[m] = __builtin_amdgcn_mfma_f32_16x16x32_bf16(afrag, bfrag, acc[m], 0, 0, 0);
        }
        __syncthreads();
    }
    const int col = c0 + wave * 16 + l15;
    float bias = loadE(b1, col, f32) + (b2 ? loadE(b2, col, f32) : 0.f);
#pragma unroll
    for (int m = 0; m < 4; ++m) {
#pragma unroll
        for (int r = 0; r < 4; ++r) {
            int row = r0 + m * 16 + q * 4 + r;
            float v = acc[m][r] + bias;
            if (outIsOutput && f32) ((float*)out)[(size_t)row * N + col] = v;
            else ((__hip_bfloat16*)out)[(size_t)row * N + col] = f2bf(v);
        }
    }
}

// ---------------- recurrence: 16 blocks = 8 groups x 2 col-halves, 512 thr.
// Blocks b and b+8 pair (same group, halves 0/1) — same XCD under round-robin.
// LDS h layout is FRAG-MAJOR: value (sample s, col j) lives at ((j>>3)*16+s)*8 + (j&7),
// so the A-frag for (c,q,l15) is a single b128 at ((c*4+q)*16+l15)*8, lane stride 16 B
// (conflict-free), and a polled 8-col run is a single b128 write.
__global__ __launch_bounds__(512, 2) void rnn_recur(
    const __hip_bfloat16* __restrict__ xp,    // [T*128][512] bf16 (ws)
    const void* __restrict__ Whh,             // [512][512] orig dtype
    const void* __restrict__ h0all,           // [2][128][512] orig dtype
    int layer,
    const int* __restrict__ lengths,          // [128] sorted desc
    __hip_bfloat16* __restrict__ out0,        // [T*128][512] bf16 or nullptr
    void* __restrict__ hout,                  // d_out base; final h at elem houtOff
    int houtOff,
    __hip_bfloat16* __restrict__ hfbf,        // [128][512] final h bf16 (logits input)
    unsigned int* __restrict__ ex,            // [8 gb][2 slot][2 p][4096] u32 tagged words
    const unsigned int* __restrict__ dflag)
{
    const int gb = blockIdx.x & 7, p = (blockIdx.x >> 3) & 1;
    const int tid = threadIdx.x, lane = tid & 63, wave = tid >> 6;
    const int q = (lane >> 4) & 3, l15 = lane & 15;
    const int colBase = p * 256 + wave * 32;   // this wave's 32 output columns
    const int s0 = gb * 16;
    const int pcPart = (1 - p) * 256;          // partner's column base
    const bool f32 = *dflag != 0;
    const size_t h0base = (size_t)layer * NBATCH * HID;
    __shared__ short hlds[2 * HB];

    // persistent B fragments: Whh[j][k], j in wave's 32 cols, full K (128 regs)
    bf16x8 bfr[2][16];
    if (f32) {
#pragma unroll
        for (int tau = 0; tau < 2; ++tau)
#pragma unroll
            for (int c = 0; c < 16; ++c) {
                const float* f = (const float*)Whh + (size_t)(colBase + tau * 16 + l15) * HID + c * 32 + q * 8;
                BF8 u;
#pragma unroll
                for (int i = 0; i < 8; ++i) u.u[i] = f2bfbits(f[i]);
                bfr[tau][c] = u.v;
            }
    } else {
#pragma unroll
        for (int tau = 0; tau < 2; ++tau)
#pragma unroll
            for (int c = 0; c < 16; ++c)
                bfr[tau][c] = *(const bf16x8*)((const __hip_bfloat16*)Whh +
                    (size_t)(colBase + tau * 16 + l15) * HID + c * 32 + q * 8);
    }

    int len_r[4];
#pragma unroll
    for (int r = 0; r < 4; ++r) len_r[r] = lengths[s0 + q * 4 + r];

    float cur[2][4];  // owned h: sample q*4+r, col colBase + tau*16 + l15
#pragma unroll
    for (int tau = 0; tau < 2; ++tau)
#pragma unroll
        for (int r = 0; r < 4; ++r)
            cur[tau][r] = loadE(h0all, h0base + (size_t)(s0 + q * 4 + r) * HID + colBase + tau * 16 + l15, f32);

    // stage FULL S_0 into LDS buf 0 (frag-major): thread covers sample sr, cols cb16..+15
    {
        const int sr = tid >> 5, cb16 = (tid & 31) * 16;
        BF8 u0, u1;
#pragma unroll
        for (int i = 0; i < 8; ++i) {
            u0.u[i] = f2bfbits(loadE(h0all, h0base + (size_t)(s0 + sr) * HID + cb16 + i, f32));
            u1.u[i] = f2bfbits(loadE(h0all, h0base + (size_t)(s0 + sr) * HID + cb16 + 8 + i, f32));
        }
        *(bf16x8*)&hlds[(((cb16 >> 3) * 16) + sr) * 8] = u0.v;
        *(bf16x8*)&hlds[((((cb16 + 8) >> 3) * 16) + sr) * 8] = u1.v;
    }
    __syncthreads();

    const int Tg = lengths[s0];   // group max length; same for both halves
    const int psr = tid >> 5;                 // poll: sample index
    const int pw = (tid * 8) & 255;           // poll: col offset within partner half
    unsigned int* exg = ex + (size_t)gb * 2 * 2 * 4096;

    // preload xp for t=0
    float xv[2][4];
    {
        const __hip_bfloat16* xprow = xp + (size_t)s0 * HID;
#pragma unroll
        for (int tau = 0; tau < 2; ++tau)
#pragma unroll
            for (int r = 0; r < 4; ++r)
                xv[tau][r] = bf2f(xprow[(size_t)(q * 4 + r) * HID + colBase + tau * 16 + l15]);
    }

    for (int t = 0; t < Tg; ++t) {
        const int cb_ = t & 1, nb = (t + 1) & 1;
        const short* hrd = &hlds[cb_ * HB];
        short* hwr = &hlds[nb * HB];

        // prefetch next step's xp (overlaps MFMA + poll)
        float xn[2][4];
        if (t + 1 < Tg) {
            const __hip_bfloat16* xprow = xp + ((size_t)(t + 1) * NBATCH + s0) * HID;
#pragma unroll
            for (int tau = 0; tau < 2; ++tau)
#pragma unroll
                for (int r = 0; r < 4; ++r)
                    xn[tau][r] = bf2f(xprow[(size_t)(q * 4 + r) * HID + colBase + tau * 16 + l15]);
        }

        f32x4 zz = {0.f, 0.f, 0.f, 0.f};
        f32x4 acc[2] = {zz, zz};
#pragma unroll
        for (int c = 0; c < 16; ++c) {
            bf16x8 a = *(const bf16x8*)&hrd[((c * 4 + q) * 16 + l15) * 8];
            acc[0] = __builtin_amdgcn_mfma_f32_16x16x32_bf16(a, bfr[0][c], acc[0], 0, 0, 0);
            acc[1] = __builtin_amdgcn_mfma_f32_16x16x32_bf16(a, bfr[1][c], acc[1], 0, 0, 0);
        }

        // h_{t+1}: tanh, publish own half FIRST (get stores on the wire), then LDS/out0
        const unsigned int tag = (unsigned int)(t + 1);
        unsigned int* exw = exg + (nb * 2 + p) * 4096;
        unsigned short bits[2][4];
#pragma unroll
        for (int tau = 0; tau < 2; ++tau)
#pragma unroll
            for (int r = 0; r < 4; ++r) {
                float hnew = fast_tanh(acc[tau][r] + xv[tau][r]);
                float val = (t < len_r[r]) ? hnew : cur[tau][r];
                cur[tau][r] = val;
                bits[tau][r] = f2bfbits(val);
                __hip_atomic_store(&exw[(q * 4 + r) * 256 + wave * 32 + tau * 16 + l15],
                                   (tag << 16) | (unsigned int)bits[tau][r],
                                   __ATOMIC_RELAXED, __HIP_MEMORY_SCOPE_AGENT);
            }
#pragma unroll
        for (int tau = 0; tau < 2; ++tau)
#pragma unroll
            for (int r = 0; r < 4; ++r) {
                const int sl = q * 4 + r;
                const int j = colBase + tau * 16 + l15;
                hwr[((j >> 3) * 16 + sl) * 8 + (j & 7)] = (short)bits[tau][r];
                if (out0 && t < len_r[r])
                    out0[((size_t)t * NBATCH + s0 + sl) * HID + j] =
                        *reinterpret_cast<__hip_bfloat16*>(&bits[tau][r]);
            }

        // poll partner's half of S_{t+1} (skip after last step)
        if (t + 1 < Tg) {
            const unsigned int* exr = exg + (nb * 2 + (1 - p)) * 4096 + tid * 8;
            uint4 va, vb;
            int spins = 0;
            for (;;) {
                load2_coherent(exr, va, vb);
                bool ok = (va.x >> 16) == tag && (va.y >> 16) == tag &&
                          (va.z >> 16) == tag && (va.w >> 16) == tag &&
                          (vb.x >> 16) == tag && (vb.y >> 16) == tag &&
                          (vb.z >> 16) == tag && (vb.w >> 16) == tag;
                if (ok) break;
                if (++spins > 4) __builtin_amdgcn_s_sleep(1);
                if (spins > (1 << 22)) break;  // failsafe vs hang
            }
            BF8 u;
            u.u[0] = (unsigned short)(va.x & 0xFFFF); u.u[1] = (unsigned short)(va.y & 0xFFFF);
            u.u[2] = (unsigned short)(va.z & 0xFFFF); u.u[3] = (unsigned short)(va.w & 0xFFFF);
            u.u[4] = (unsigned short)(vb.x & 0xFFFF); u.u[5] = (unsigned short)(vb.y & 0xFFFF);
            u.u[6] = (unsigned short)(vb.z & 0xFFFF); u.u[7] = (unsigned short)(vb.w & 0xFFFF);
            const int jp = pcPart + pw;  // 8-aligned col run, sample psr
            *(bf16x8*)&hwr[((jp >> 3) * 16 + psr) * 8] = u.v;
        }
        __syncthreads();
#pragma unroll
        for (int tau = 0; tau < 2; ++tau)
#pragma unroll
            for (int r = 0; r < 4; ++r) xv[tau][r] = xn[tau][r];
    }

    // finals: h to d_out (output dtype) + bf16 copy for logits GEMM
#pragma unroll
    for (int tau = 0; tau < 2; ++tau)
#pragma unroll
        for (int r = 0; r < 4; ++r) {
            size_t idx = (size_t)(s0 + q * 4 + r) * HID + colBase + tau * 16 + l15;
            if (f32) ((float*)hout)[houtOff + idx] = cur[tau][r];
            else     ((__hip_bfloat16*)hout)[houtOff + idx] = f2bf(cur[tau][r]);
            hfbf[idx] = f2bf(cur[tau][r]);
        }
}

extern "C" void kernel_launch(void* const* d_in, const int* in_sizes, int n_in,
                              void* d_out, int out_size, void* d_ws, size_t ws_size,
                              hipStream_t stream) {
    const void* x    = d_in[0];
    const void* h0   = d_in[1];
    const int*  lens = (const int*)d_in[2];
    const void* Wih0 = d_in[3];
    const void* bih0 = d_in[4];
    const void* Whh0 = d_in[5];
    const void* bhh0 = d_in[6];
    const void* Wih1 = d_in[7];
    const void* bih1 = d_in[8];
    const void* Whh1 = d_in[9];
    const void* bhh1 = d_in[10];
    const void* Wfc  = d_in[11];
    const void* bfc  = d_in[12];

    const size_t MROWS = (size_t)T_STEPS * NBATCH;          // 65536
    size_t off = 0;
    auto take = [&](size_t bytes) { size_t o = off; off += (bytes + 255) & ~255ull; return o; };
    const size_t off_xp   = take(MROWS * HID * 2);          // 64 MB bf16
    const size_t off_out0 = take(MROWS * HID * 2);          // 64 MB bf16
    const size_t EX_WORDS_PER_LAYER = 8ull * 2 * 2 * 4096;  // 131072
    const size_t off_ex   = take(2 * EX_WORDS_PER_LAYER * 4);
    const size_t off_hfbf = take(2ull * NBATCH * HID * 2);
    const size_t off_dfl  = take(256);
    if (ws_size < off) return;  // workspace too small

    char* ws = (char*)d_ws;
    __hip_bfloat16* xp    = (__hip_bfloat16*)(ws + off_xp);
    __hip_bfloat16* out0  = (__hip_bfloat16*)(ws + off_out0);
    unsigned int*   ex    = (unsigned int*)(ws + off_ex);
    __hip_bfloat16* hfbf  = (__hip_bfloat16*)(ws + off_hfbf);
    unsigned int*   dflag = (unsigned int*)(ws + off_dfl);

    // no memset of ex needed: poison 0xAAAA tag matches no step tag (1..512)
    detect_dtype<<<1, 64, 0, stream>>>((const unsigned short*)x, dflag);

    // layer 0 input GEMM: xp0 = x @ Wih0^T + bih0 + bhh0
    gemm_bt64<<<dim3(HID / 64, MROWS / 64), 256, 0, stream>>>(
        x, Wih0, bih0, bhh0, xp, (int)MROWS, HID, INSZ, lens, dflag, 1, 0);
    // layer 0 recurrence (writes out0 + final h into d_out at elem 16384)
    rnn_recur<<<16, 512, 0, stream>>>(
        xp, Whh0, h0, 0, lens, out0, d_out, NBATCH * 128, hfbf, ex, dflag);
    // layer 1 input GEMM: xp1 = out0 @ Wih1^T + bih1 + bhh1 (reuse xp region)
    gemm_bt64<<<dim3(HID / 64, MROWS / 64), 256, 0, stream>>>(
        out0, Wih1, bih1, bhh1, xp, (int)MROWS, HID, HID, lens, dflag, 0, 0);
    // layer 1 recurrence (final h into d_out at elem 16384 + 65536)
    rnn_recur<<<16, 512, 0, stream>>>(
        xp, Whh1, h0, 1, lens, nullptr, d_out,
        NBATCH * 128 + NBATCH * HID, hfbf + (size_t)NBATCH * HID,
        ex + EX_WORDS_PER_LAYER, dflag);
    // logits = h1_final @ Wfc^T + bfc
    gemm_bt64<<<dim3(2, 2), 256, 0, stream>>>(
        hfbf + (size_t)NBATCH * HID, Wfc, bfc, nullptr,
        d_out, NBATCH, 128, HID, nullptr, dflag, 0, 1);
}